// Round 6
// baseline (387.600 us; speedup 1.0000x reference)
//
#include <hip/hip_runtime.h>
#include <hip/hip_cooperative_groups.h>

namespace cg = cooperative_groups;

// Problem constants (from reference): N=65536 rows, A=512 features, C=1000 classes.
constexpr int N_ROWS  = 65536;
constexpr int N_FEAT  = 512;
constexpr int N_FEAT4 = N_FEAT / 4;   // float4 per row = 128
constexpr int N_CLS   = 1000;
constexpr int GRID    = 512;          // class-strided phase 4; coop-capacity safe
constexpr int BLOCK   = 256;
constexpr int HIST_BLOCKS = 64;       // blocks doing partial histograms (1024 rows each)

// Workspace layout (bytes):
//   [0,      8192)   int offs[1025]         exclusive prefix offsets
//   [8192,  12288)   int cursor[1024]       scatter cursors
//   [12288, 274432)  int perm[65536]        row indices grouped by class
//   [274432,536576)  int partials[64][1024] per-block histograms (no zeroing needed)

// __launch_bounds__(256, 2): min 2 blocks/CU -> VGPR capped at 256 (no spill
// risk for this loop) and cooperative co-residency capacity >= 512 == GRID.
__global__ __launch_bounds__(BLOCK, 2) void estimator_all(
    const float* __restrict__ features,
    const int*   __restrict__ labels,
    const float* __restrict__ count,
    const float* __restrict__ mean,
    const float* __restrict__ cov,
    float*       __restrict__ out,
    int* __restrict__ offs,
    int* __restrict__ cursor,
    int* __restrict__ perm,
    int* __restrict__ partials)
{
    cg::grid_group grid = cg::this_grid();
    const int b = blockIdx.x, t = threadIdx.x;
    // LDS overlay: P1 uses 4KB bins; P2 uses 4 ints; P4 uses sh(1KB)+red_s(2KB)+red_q(2KB)
    __shared__ __align__(16) char smem[5120];

    // ---- Phase 1: per-block partial histograms (blocks 0..63, 1024 rows each) ----
    if (b < HIST_BLOCKS) {
        int* lbins = (int*)smem;                       // 1024 ints
        lbins[t] = 0; lbins[t+256] = 0; lbins[t+512] = 0; lbins[t+768] = 0;
        __syncthreads();
        const int4 v = ((const int4*)labels)[b * BLOCK + t];
        atomicAdd(&lbins[v.x], 1); atomicAdd(&lbins[v.y], 1);
        atomicAdd(&lbins[v.z], 1); atomicAdd(&lbins[v.w], 1);
        __syncthreads();
        ((int4*)&partials[b * 1024])[t] = ((const int4*)lbins)[t];  // non-atomic
    }
    grid.sync();

    // ---- Phase 2: merge partials + exclusive scan over 1024 bins (block 0) ----
    if (b == 0) {
        int v0 = 0, v1 = 0, v2 = 0, v3 = 0;            // counts of bins 4t..4t+3
        const int4* p4 = (const int4*)partials;
        #pragma unroll 8
        for (int k = 0; k < HIST_BLOCKS; ++k) {
            const int4 pv = p4[k * 256 + t];
            v0 += pv.x; v1 += pv.y; v2 += pv.z; v3 += pv.w;
        }
        const int T = v0 + v1 + v2 + v3;
        int inc = T;
        const int lane = t & 63;
        #pragma unroll
        for (int d = 1; d < 64; d <<= 1) {             // wave-inclusive scan, no barriers
            const int x = __shfl_up(inc, d, 64);
            if (lane >= d) inc += x;
        }
        int* wtot = (int*)smem;                        // 4 wave totals
        __syncthreads();
        if (lane == 63) wtot[t >> 6] = inc;
        __syncthreads();
        int base = 0;
        const int w = t >> 6;
        for (int k = 0; k < w; ++k) base += wtot[k];
        const int excl = base + inc - T;               // exclusive over threads
        int4 o; o.x = excl; o.y = excl + v0; o.z = o.y + v1; o.w = o.z + v2;
        ((int4*)offs)[t]   = o;
        ((int4*)cursor)[t] = o;
        if (t == 0) offs[1024] = N_ROWS;
    }
    grid.sync();

    // ---- Phase 3: scatter row indices grouped by class (blocks 0..255) ----
    if (b < 256) {
        const int i = b * BLOCK + t;
        const int l = labels[i];
        perm[atomicAdd(&cursor[l], 1)] = i;
    }
    grid.sync();

    // ---- Phase 4: per-class reduction + fused epilogue, classes strided by GRID ----
    const int half = t >> 7;          // which row of the pair
    const int col  = t & 127;         // float4 column index
    const float4* __restrict__ f4 = (const float4*)features;

    int*    sh    = (int*)smem;                 // 256 ints
    float4* red_s = (float4*)(smem + 1024);     // 128 float4
    float4* red_q = (float4*)(smem + 3072);     // 128 float4

    for (int c = b; c < N_CLS; c += GRID) {
        const int start = offs[c];
        const int n = offs[c + 1] - start;

        float s0 = 0.f, s1 = 0.f, s2 = 0.f, s3 = 0.f;
        float q0 = 0.f, q1 = 0.f, q2 = 0.f, q3 = 0.f;

        for (int base = 0; base < n; base += 256) {
            const int chunk = min(256, n - base);
            __syncthreads();
            if (t < chunk) sh[t] = perm[start + base + t];
            __syncthreads();
            int j = 0;
            for (; j + 16 <= chunk; j += 16) {      // 8 independent 16B loads/lane
                const int r0 = sh[j +  0 + half], r1 = sh[j +  2 + half];
                const int r2 = sh[j +  4 + half], r3 = sh[j +  6 + half];
                const int r4 = sh[j +  8 + half], r5 = sh[j + 10 + half];
                const int r6 = sh[j + 12 + half], r7 = sh[j + 14 + half];
                const float4 v0 = f4[(size_t)r0 * N_FEAT4 + col];
                const float4 v1 = f4[(size_t)r1 * N_FEAT4 + col];
                const float4 v2 = f4[(size_t)r2 * N_FEAT4 + col];
                const float4 v3 = f4[(size_t)r3 * N_FEAT4 + col];
                const float4 v4 = f4[(size_t)r4 * N_FEAT4 + col];
                const float4 v5 = f4[(size_t)r5 * N_FEAT4 + col];
                const float4 v6 = f4[(size_t)r6 * N_FEAT4 + col];
                const float4 v7 = f4[(size_t)r7 * N_FEAT4 + col];
                #define ACC(v) \
                    s0 += v.x; q0 = fmaf(v.x, v.x, q0); \
                    s1 += v.y; q1 = fmaf(v.y, v.y, q1); \
                    s2 += v.z; q2 = fmaf(v.z, v.z, q2); \
                    s3 += v.w; q3 = fmaf(v.w, v.w, q3);
                ACC(v0) ACC(v1) ACC(v2) ACC(v3) ACC(v4) ACC(v5) ACC(v6) ACC(v7)
                #undef ACC
            }
            if (j < chunk) {                        // weighted remainder
                #pragma unroll
                for (int u = 0; u < 8; ++u) {
                    const int idx = j + 2 * u + half;
                    const int r = (idx < chunk) ? sh[idx] : sh[j];
                    const float w = (idx < chunk) ? 1.f : 0.f;
                    const float4 v = f4[(size_t)r * N_FEAT4 + col];
                    const float vx = v.x * w, vy = v.y * w, vz = v.z * w, vw = v.w * w;
                    s0 += vx; q0 = fmaf(vx, v.x, q0);
                    s1 += vy; q1 = fmaf(vy, v.y, q1);
                    s2 += vz; q2 = fmaf(vz, v.z, q2);
                    s3 += vw; q3 = fmaf(vw, v.w, q3);
                }
            }
        }

        __syncthreads();
        if (half == 1) {
            red_s[col] = make_float4(s0, s1, s2, s3);
            red_q[col] = make_float4(q0, q1, q2, q3);
        }
        __syncthreads();
        if (half == 0) {
            const float4 rs = red_s[col], rq = red_q[col];
            s0 += rs.x; s1 += rs.y; s2 += rs.z; s3 += rs.w;
            q0 += rq.x; q1 += rq.y; q2 += rq.z; q3 += rq.w;

            const float fn  = (float)n;
            const float amt = (n > 0) ? fn : 1.0f;
            const float inv = 1.0f / amt;
            const float a0 = s0 * inv, a1 = s1 * inv, a2 = s2 * inv, a3 = s3 * inv;
            const float vr0 = q0 * inv - a0 * a0;   // E[x^2]-E[x]^2
            const float vr1 = q1 * inv - a1 * a1;
            const float vr2 = q2 * inv - a2 * a2;
            const float vr3 = q3 * inv - a3 * a3;

            const float cnt   = count[c];
            const float denom = fn + cnt;
            const float w     = (denom == 0.f) ? 0.f : fn / denom;
            const float omw   = 1.0f - w;

            const float4 mv = ((const float4*)mean)[c * N_FEAT4 + col];
            const float4 cv = ((const float4*)cov)[c * N_FEAT4 + col];
            const float d0 = mv.x - a0, d1 = mv.y - a1, d2 = mv.z - a2, d3 = mv.w - a3;

            float4 covn, meann;
            covn.x  = cv.x * omw + vr0 * w + w * omw * d0 * d0;
            covn.y  = cv.y * omw + vr1 * w + w * omw * d1 * d1;
            covn.z  = cv.z * omw + vr2 * w + w * omw * d2 * d2;
            covn.w  = cv.w * omw + vr3 * w + w * omw * d3 * d3;
            meann.x = mv.x * omw + a0 * w;
            meann.y = mv.y * omw + a1 * w;
            meann.z = mv.z * omw + a2 * w;
            meann.w = mv.w * omw + a3 * w;

            ((float4*)out)[c * N_FEAT4 + col] = covn;                      // cov_new
            ((float4*)(out + N_CLS * N_FEAT))[c * N_FEAT4 + col] = meann;  // mean_new
            if (t == 0) out[2 * N_CLS * N_FEAT + c] = cnt + fn;            // count_new
        }
    }
}

extern "C" void kernel_launch(void* const* d_in, const int* in_sizes, int n_in,
                              void* d_out, int out_size, void* d_ws, size_t ws_size,
                              hipStream_t stream) {
    const float* features = (const float*)d_in[0];
    const int*   labels   = (const int*)d_in[1];
    const float* count    = (const float*)d_in[2];
    const float* mean     = (const float*)d_in[3];
    const float* cov      = (const float*)d_in[4];
    float* out = (float*)d_out;

    char* ws = (char*)d_ws;
    int* offs     = (int*)(ws + 0);        // 1025 ints
    int* cursor   = (int*)(ws + 8192);     // 1024 ints
    int* perm     = (int*)(ws + 12288);    // 65536 ints
    int* partials = (int*)(ws + 274432);   // 64*1024 ints

    void* args[] = { &features, &labels, &count, &mean, &cov, &out,
                     &offs, &cursor, &perm, &partials };
    hipLaunchCooperativeKernel((const void*)estimator_all,
                               dim3(GRID), dim3(BLOCK), args, 0, stream);
}

// Round 7
// 227.292 us; speedup vs baseline: 1.7053x; 1.7053x over previous
//
#include <hip/hip_runtime.h>

// Problem constants (from reference): N=65536 rows, A=512 features, C=1000 classes.
constexpr int N_ROWS  = 65536;
constexpr int N_FEAT  = 512;
constexpr int N_FEAT4 = N_FEAT / 4;   // float4 per row = 128
constexpr int N_CLS   = 1000;
constexpr int HIST_BLOCKS = 64;

// Workspace layout (bytes):
//   [0,      8192)   int offs[1025]         exclusive prefix offsets
//   [8192,  12288)   int cursor[1024]       scatter cursors
//   [12288, 274432)  int perm[65536]        row indices grouped by class
//   [274432,536576)  int partials[64][1024] per-block histograms (no zeroing needed)

// ---- Kernel 1: per-block partial histograms (non-atomic global writes) ----
__global__ __launch_bounds__(256) void hist_kernel(
    const int* __restrict__ labels, int* __restrict__ partials)
{
    __shared__ int lbins[1024];
    const int t = threadIdx.x, b = blockIdx.x;
    lbins[t] = 0; lbins[t+256] = 0; lbins[t+512] = 0; lbins[t+768] = 0;
    __syncthreads();
    const int4 v = ((const int4*)labels)[b * 256 + t];   // 1024 rows per block
    atomicAdd(&lbins[v.x], 1); atomicAdd(&lbins[v.y], 1);
    atomicAdd(&lbins[v.z], 1); atomicAdd(&lbins[v.w], 1);
    __syncthreads();
    ((int4*)&partials[b * 1024])[t] = ((const int4*)lbins)[t];
}

// ---- Kernel 2: merge 64 partials + exclusive scan over 1024 bins (1 block) ----
__global__ __launch_bounds__(256) void scan_kernel(
    const int* __restrict__ partials, int* __restrict__ offs, int* __restrict__ cursor)
{
    __shared__ int wtot[4];
    const int t = threadIdx.x;
    int v0 = 0, v1 = 0, v2 = 0, v3 = 0;                  // bins 4t..4t+3
    const int4* p4 = (const int4*)partials;
    #pragma unroll 8
    for (int k = 0; k < HIST_BLOCKS; ++k) {
        const int4 pv = p4[k * 256 + t];
        v0 += pv.x; v1 += pv.y; v2 += pv.z; v3 += pv.w;
    }
    const int T = v0 + v1 + v2 + v3;
    int inc = T;
    const int lane = t & 63;
    #pragma unroll
    for (int d = 1; d < 64; d <<= 1) {                   // wave-inclusive scan
        const int x = __shfl_up(inc, d, 64);
        if (lane >= d) inc += x;
    }
    if (lane == 63) wtot[t >> 6] = inc;
    __syncthreads();
    int base = 0;
    const int w = t >> 6;
    for (int k = 0; k < w; ++k) base += wtot[k];
    const int excl = base + inc - T;
    int4 o; o.x = excl; o.y = excl + v0; o.z = o.y + v1; o.w = o.z + v2;
    ((int4*)offs)[t]   = o;
    ((int4*)cursor)[t] = o;
    if (t == 0) offs[1024] = N_ROWS;
}

// ---- Kernel 3: scatter row indices grouped by class ----
__global__ __launch_bounds__(256) void scatter_kernel(
    const int* __restrict__ labels, int* __restrict__ cursor, int* __restrict__ perm)
{
    const int i = blockIdx.x * blockDim.x + threadIdx.x;   // one int4 (4 rows)/thread
    const int4 v = ((const int4*)labels)[i];
    const int r = i * 4;
    perm[atomicAdd(&cursor[v.x], 1)] = r + 0;
    perm[atomicAdd(&cursor[v.y], 1)] = r + 1;
    perm[atomicAdd(&cursor[v.z], 1)] = r + 2;
    perm[atomicAdd(&cursor[v.w], 1)] = r + 3;
}

// ---- Kernel 4: per-class reduction + fused epilogue ----
// Grid = 1000 classes x 2 column-halves = 2000 blocks (~7.8 blocks/CU, full
// 32-wave residency). 256 threads = 4 row-slots x 64 lanes; each lane owns one
// float4 column (16 B/lane, wave covers 1 KB contiguous). 4 independent row
// loads in flight per thread; cross-slot LDS reduce; fused epilogue.
__global__ __launch_bounds__(256) void estimator_main(
    const float* __restrict__ features,
    const float* __restrict__ count,
    const float* __restrict__ mean,
    const float* __restrict__ cov,
    const int* __restrict__ offs,
    const int* __restrict__ perm,
    float* __restrict__ out)
{
    const int blk = blockIdx.x;
    const int c   = blk >> 1;          // class
    const int ch  = blk & 1;           // column half
    const int t    = threadIdx.x;
    const int slot = t >> 6;           // 0..3: row within quad
    const int lane = t & 63;
    const int col  = (ch << 6) | lane; // float4 column 0..127
    const int start = offs[c];
    const int n = offs[c + 1] - start;

    __shared__ int sh[256];
    __shared__ float4 red_s[3][64];
    __shared__ float4 red_q[3][64];

    const float4* __restrict__ f4 = (const float4*)features;

    float s0 = 0.f, s1 = 0.f, s2 = 0.f, s3 = 0.f;
    float q0 = 0.f, q1 = 0.f, q2 = 0.f, q3 = 0.f;

    for (int base = 0; base < n; base += 256) {
        const int chunk = min(256, n - base);
        __syncthreads();
        if (t < chunk) sh[t] = perm[start + base + t];
        __syncthreads();
        int j = 0;
        for (; j + 16 <= chunk; j += 16) {     // 4 independent 16B loads/lane
            const int r0 = sh[j      + slot];
            const int r1 = sh[j +  4 + slot];
            const int r2 = sh[j +  8 + slot];
            const int r3 = sh[j + 12 + slot];
            const float4 v0 = f4[(size_t)r0 * N_FEAT4 + col];
            const float4 v1 = f4[(size_t)r1 * N_FEAT4 + col];
            const float4 v2 = f4[(size_t)r2 * N_FEAT4 + col];
            const float4 v3 = f4[(size_t)r3 * N_FEAT4 + col];
            #define ACC(v) \
                s0 += v.x; q0 = fmaf(v.x, v.x, q0); \
                s1 += v.y; q1 = fmaf(v.y, v.y, q1); \
                s2 += v.z; q2 = fmaf(v.z, v.z, q2); \
                s3 += v.w; q3 = fmaf(v.w, v.w, q3);
            ACC(v0) ACC(v1) ACC(v2) ACC(v3)
            #undef ACC
        }
        if (j < chunk) {                       // weighted remainder (<=15 rows)
            #pragma unroll
            for (int u = 0; u < 4; ++u) {
                const int idx = j + 4 * u + slot;
                const int r = (idx < chunk) ? sh[idx] : sh[j];
                const float w = (idx < chunk) ? 1.f : 0.f;
                const float4 v = f4[(size_t)r * N_FEAT4 + col];
                const float vx = v.x * w, vy = v.y * w, vz = v.z * w, vw = v.w * w;
                s0 += vx; q0 = fmaf(vx, v.x, q0);
                s1 += vy; q1 = fmaf(vy, v.y, q1);
                s2 += vz; q2 = fmaf(vz, v.z, q2);
                s3 += vw; q3 = fmaf(vw, v.w, q3);
            }
        }
    }

    __syncthreads();
    if (slot != 0) {
        red_s[slot - 1][lane] = make_float4(s0, s1, s2, s3);
        red_q[slot - 1][lane] = make_float4(q0, q1, q2, q3);
    }
    __syncthreads();
    if (slot == 0) {
        #pragma unroll
        for (int k = 0; k < 3; ++k) {
            const float4 rs = red_s[k][lane], rq = red_q[k][lane];
            s0 += rs.x; s1 += rs.y; s2 += rs.z; s3 += rs.w;
            q0 += rq.x; q1 += rq.y; q2 += rq.z; q3 += rq.w;
        }

        const float fn  = (float)n;
        const float amt = (n > 0) ? fn : 1.0f;
        const float inv = 1.0f / amt;
        const float a0 = s0 * inv, a1 = s1 * inv, a2 = s2 * inv, a3 = s3 * inv;
        const float vr0 = q0 * inv - a0 * a0;  // E[x^2]-E[x]^2 == segsum((x-ave)^2)/amt
        const float vr1 = q1 * inv - a1 * a1;
        const float vr2 = q2 * inv - a2 * a2;
        const float vr3 = q3 * inv - a3 * a3;

        const float cnt   = count[c];
        const float denom = fn + cnt;
        const float w     = (denom == 0.f) ? 0.f : fn / denom;
        const float omw   = 1.0f - w;

        const float4 mv = ((const float4*)mean)[c * N_FEAT4 + col];
        const float4 cv = ((const float4*)cov)[c * N_FEAT4 + col];
        const float d0 = mv.x - a0, d1 = mv.y - a1, d2 = mv.z - a2, d3 = mv.w - a3;

        float4 covn, meann;
        covn.x  = cv.x * omw + vr0 * w + w * omw * d0 * d0;
        covn.y  = cv.y * omw + vr1 * w + w * omw * d1 * d1;
        covn.z  = cv.z * omw + vr2 * w + w * omw * d2 * d2;
        covn.w  = cv.w * omw + vr3 * w + w * omw * d3 * d3;
        meann.x = mv.x * omw + a0 * w;
        meann.y = mv.y * omw + a1 * w;
        meann.z = mv.z * omw + a2 * w;
        meann.w = mv.w * omw + a3 * w;

        ((float4*)out)[c * N_FEAT4 + col] = covn;                      // cov_new  [C,A]
        ((float4*)(out + N_CLS * N_FEAT))[c * N_FEAT4 + col] = meann;  // mean_new [C,A]
        if (t == 0 && ch == 0) out[2 * N_CLS * N_FEAT + c] = cnt + fn; // count_new [C]
    }
}

extern "C" void kernel_launch(void* const* d_in, const int* in_sizes, int n_in,
                              void* d_out, int out_size, void* d_ws, size_t ws_size,
                              hipStream_t stream) {
    const float* features = (const float*)d_in[0];
    const int*   labels   = (const int*)d_in[1];
    const float* count    = (const float*)d_in[2];
    const float* mean     = (const float*)d_in[3];
    const float* cov      = (const float*)d_in[4];
    float* out = (float*)d_out;

    char* ws = (char*)d_ws;
    int* offs     = (int*)(ws + 0);        // 1025 ints
    int* cursor   = (int*)(ws + 8192);     // 1024 ints
    int* perm     = (int*)(ws + 12288);    // 65536 ints
    int* partials = (int*)(ws + 274432);   // 64*1024 ints

    hist_kernel<<<HIST_BLOCKS, 256, 0, stream>>>(labels, partials);
    scan_kernel<<<1, 256, 0, stream>>>(partials, offs, cursor);
    scatter_kernel<<<N_ROWS / 4 / 256, 256, 0, stream>>>(labels, cursor, perm);
    estimator_main<<<2 * N_CLS, 256, 0, stream>>>(features, count, mean, cov,
                                                  offs, perm, out);
}